// Round 11
// baseline (875.000 us; speedup 1.0000x reference)
//
#include <hip/hip_runtime.h>
#include <math.h>

#define NA    360
#define ZPT   8
#define PR    24            // staged rows per copy (24-row v-window proven in R5)
#define PITCH 66            // floats: 264B rows -> 8B-aligned, bank=(2v0+u)&31 spread
#define COPYF (PR*PITCH)    // 1584 floats per copy
#define NSTG  (2*COPYF)     // copyA (u_lo..u_lo+63) + copyB (u_lo+1..u_lo+64)
#define VLO_MAX 232         // rows vlo..vlo+23 <= 255
#define ULO_MAX 191         // copyB col u_lo+64 <= 255 -> staged bytes stay in-slab

// Cone-beam backprojection. LDS-staged, dual u-phase copies, b64 taps.
// Geometry: dz=dy=dx=2mm, dv=du=2mm, DSO=1000, DSD=1536, mag in [1.302,1.872].
// iv = zv*mag + 127.5 in (8.6,246.4) -> v never clamps, v0+1 in-bounds.
// Bilinear taps (u0,u0+1) at rows v0,v0+1: local u parity selects the copy in
// which the pair is 8B-aligned -> two ds_read_b64 (264B apart -> fusable into
// one ds_read2_b64). Halves LDS bank accesses vs 2x ds_read2_b32 (the R8-R10
// measured floor: LDS-pipe bound, occupancy insensitive).

typedef float v2f __attribute__((ext_vector_type(2)));
typedef __attribute__((address_space(1))) const void gas_t;
typedef __attribute__((address_space(3))) void las_t;

struct __align__(16) Ang { float c, s; int ulo, vlo; };

__device__ __forceinline__ Ang ang_setup(int i, float xclo, float xchi,
                                         float yclo, float ychi,
                                         float zvlo, float zvhi)
{
    float th = (float)i * (float)(2.0 * M_PI / (double)NA);
    float s, c; sincosf(th, &s, &c);
    const float a0 = xclo*c, a1 = xchi*c, b0 = yclo*s, b1 = ychi*s;
    const float xr0 = a0+b0, xr1 = a0+b1, xr2 = a1+b0, xr3 = a1+b1;
    const float xmn = fminf(fminf(xr0,xr1), fminf(xr2,xr3));
    const float xmx = fmaxf(fmaxf(xr0,xr1), fmaxf(xr2,xr3));
    const float c0 = yclo*c, c1 = ychi*c, d0 = xclo*s, d1 = xchi*s;
    const float yr0 = c0-d0, yr1 = c0-d1, yr2 = c1-d0, yr3 = c1-d1;
    const float ymn = fminf(fminf(yr0,yr1), fminf(yr2,yr3));
    const float ymx = fmaxf(fmaxf(yr0,yr1), fmaxf(yr2,yr3));
    const float mlo = 1536.f * __builtin_amdgcn_rcpf(1000.f - xmn);
    const float mhi = 1536.f * __builtin_amdgcn_rcpf(1000.f - xmx);
    const float umn = fminf(fminf(ymn*mlo, ymn*mhi), fminf(ymx*mlo, ymx*mhi));
    int u_lo = (int)floorf(fmaf(umn, 0.5f, 127.5f)) - 1;
    u_lo = u_lo < 0 ? 0 : (u_lo > ULO_MAX ? ULO_MAX : u_lo);
    const float vmn = fminf(fminf(zvlo*mlo, zvlo*mhi), fminf(zvhi*mlo, zvhi*mhi));
    int v_lo = (int)floorf(vmn + 127.5f) - 1;
    v_lo = v_lo < 0 ? 0 : (v_lo > VLO_MAX ? VLO_MAX : v_lo);
    Ang g; g.c = c; g.s = s; g.ulo = u_lo; g.vlo = v_lo;
    return g;
}

// Wave w stages rows w*6..w*6+5 of both copies. pb = slab + angle-base + w*6144
// + lane*4 (per-lane). Row j: copyA from +j*1024, copyB from +j*1024+4.
// Imm offsets kept < 4096 by splitting the base at j=4.
__device__ __forceinline__ void stage_angle(const char* pb, float* la) {
    float* lb = la + COPYF;
    const char* pb1 = pb + 4096;
    #pragma unroll
    for (int j = 0; j < 4; ++j) {
        __builtin_amdgcn_global_load_lds((gas_t*)(pb + j*1024),
                                         (las_t*)(la + j*PITCH), 4, 0, 0);
        __builtin_amdgcn_global_load_lds((gas_t*)(pb + j*1024 + 4),
                                         (las_t*)(lb + j*PITCH), 4, 0, 0);
    }
    #pragma unroll
    for (int j = 0; j < 2; ++j) {
        __builtin_amdgcn_global_load_lds((gas_t*)(pb1 + j*1024),
                                         (las_t*)(la + (j+4)*PITCH), 4, 0, 0);
        __builtin_amdgcn_global_load_lds((gas_t*)(pb1 + j*1024 + 4),
                                         (las_t*)(lb + (j+4)*PITCH), 4, 0, 0);
    }
}

__device__ __forceinline__ void compute_angle(const float* __restrict__ smb,
    const Ang g, float xc, float yc, float zf0, v2f acc[ZPT])
{
    const float xr  = xc*g.c + yc*g.s;
    const float yr  = yc*g.c - xc*g.s;
    const float mag = 1536.f * __builtin_amdgcn_rcpf(1000.f - xr);
    const float iu  = fmaf(yr*mag, 0.5f, 127.5f);
    const bool uval = (iu >= 0.f) && (iu <= 255.f);
    const float iuc = fminf(fmaxf(iu, 0.f), 255.f);
    int u0 = (int)iuc; u0 = u0 > 254 ? 254 : u0;
    const float fu  = iuc - (float)u0;
    const float w   = uval ? 1.f : 0.f;
    const float wu1 = fu*w, wu0 = w - wu1;
    const v2f   wuv = {wu0, wu1};
    const int  uloc = u0 - g.ulo;                 // 0..63
    const int  sel  = uloc & 1;                   // parity picks the aligned copy
    const float* sb = smb + (uloc - sel) + sel * COPYF;
    const float ivb = fmaf(zf0, mag, 127.5f) - (float)g.vlo;
    #pragma unroll
    for (int k = 0; k < ZPT; ++k) {
        const float ivl = fmaf((float)k, mag, ivb);
        const int   v0  = (int)ivl;               // >0 -> trunc==floor
        const float fv  = ivl - (float)v0;
        const float* r  = sb + v0 * PITCH;
        v2f p0 = *(const v2f*)r;                  // ds_read_b64 (8B-aligned)
        v2f p1 = *(const v2f*)(r + PITCH);        // +264B -> fuses to ds_read2_b64
        const v2f fvv = {fv, fv};
        const v2f q = __builtin_elementwise_fma(fvv, p1 - p0, p0);
        acc[k] = __builtin_elementwise_fma(wuv, q, acc[k]);
    }
}

__global__ __launch_bounds__(256, 5) void bp_kernel(const float* __restrict__ proj,
                                                    float* __restrict__ out) {
    __shared__ Ang   ang_sh[NA];
    __shared__ float patch[2][NSTG];

    const int tid = threadIdx.y * 16 + threadIdx.x;

    const int zg = blockIdx.x;            // z-group (16)
    const int t  = blockIdx.y;            // xy tile (64)
    const int b  = blockIdx.z;
    const int x0 = (t & 7) * 16;
    const int y0 = (t >> 3) * 16;
    const int zb = zg * ZPT;

    const float zf0  = (float)zb - 63.5f;
    const float xclo = ((float)x0 - 63.5f) * 2.f, xchi = xclo + 30.f;
    const float yclo = ((float)y0 - 63.5f) * 2.f, ychi = yclo + 30.f;

    for (int i = tid; i < NA; i += 256)
        ang_sh[i] = ang_setup(i, xclo, xchi, yclo, ychi, zf0, zf0 + 7.f);
    __syncthreads();

    const int woff = (tid >> 6) * 6144 + (tid & 63) * 4;   // wave slab + lane
    const char* projB = (const char*)(proj + (size_t)b * (NA * 65536));
    const float xc = ((float)(x0 + threadIdx.x) - 63.5f) * 2.f;
    const float yc = ((float)(y0 + threadIdx.y) - 63.5f) * 2.f;

    float* l0 = &patch[0][(tid >> 6) * (6 * PITCH)];
    float* l1 = &patch[1][(tid >> 6) * (6 * PITCH)];

    v2f acc[ZPT];
    #pragma unroll
    for (int k = 0; k < ZPT; ++k) acc[k] = (v2f){0.f, 0.f};

    // prologue: stage angle 0 into patch[0]
    {
        const Ang g = ang_sh[0];
        const uint32_t aoff = __builtin_amdgcn_readfirstlane(
            ((uint32_t)g.vlo << 10) + ((uint32_t)g.ulo << 2));
        stage_angle(projB + aoff + woff, l0);
    }
    __syncthreads();   // implicit vmcnt(0) drain -> patch[0] ready

    for (int a = 0; a < NA; a += 2) {
        {   // stage a+1 -> patch[1] while computing a from patch[0]
            const Ang g = ang_sh[a + 1];
            const uint32_t aoff = __builtin_amdgcn_readfirstlane(
                (uint32_t)(a + 1) * 262144u +
                ((uint32_t)g.vlo << 10) + ((uint32_t)g.ulo << 2));
            stage_angle(projB + aoff + woff, l1);
        }
        compute_angle(patch[0], ang_sh[a], xc, yc, zf0, acc);
        __syncthreads();
        if (a + 2 < NA) {   // stage a+2 -> patch[0] while computing a+1
            const Ang g = ang_sh[a + 2];
            const uint32_t aoff = __builtin_amdgcn_readfirstlane(
                (uint32_t)(a + 2) * 262144u +
                ((uint32_t)g.vlo << 10) + ((uint32_t)g.ulo << 2));
            stage_angle(projB + aoff + woff, l0);
        }
        compute_angle(patch[1], ang_sh[a + 1], xc, yc, zf0, acc);
        __syncthreads();
    }

    float* o = out + (((size_t)b * 128 + zb) * 128 + (y0 + threadIdx.y)) * 128
                   + (x0 + threadIdx.x);
    #pragma unroll
    for (int k = 0; k < ZPT; ++k) {
        o[(size_t)k * (128 * 128)] = acc[k].x + acc[k].y;
    }
}

extern "C" void kernel_launch(void* const* d_in, const int* in_sizes, int n_in,
                              void* d_out, int out_size, void* d_ws, size_t ws_size,
                              hipStream_t stream) {
    const float* proj = (const float*)d_in[0];
    float* out = (float*)d_out;
    dim3 grid(128 / ZPT, 64, 2);   // (z-groups, xy-tiles, batch) = 2048 blocks
    dim3 block(16, 16, 1);
    hipLaunchKernelGGL(bp_kernel, grid, block, 0, stream, proj, out);
}

// Round 12
// 842.954 us; speedup vs baseline: 1.0380x; 1.0380x over previous
//
#include <hip/hip_runtime.h>
#include <math.h>

#define NA    360
#define ZPT   8
#define PITCH 65            // floats; bank=(v+u)&31 -> v-scatter spreads banks
#define NSTG  2048          // staged floats (flat; rows 0..31 of pitch-65 layout)
#define VLO_MAX 224         // stage rows vlo..vlo+31 <= 255
#define ULO_MAX 191         // stage cols ulo..ulo+64 <= 255; ui<=63, u1-tap<=64 staged

// Cone-beam backprojection, LDS-staged, pitch-65 anti-conflict layout.
// Geometry: dz=dy=dx=2mm, dv=du=2mm, DSO=1000, DSD=1536, mag in [1.302,1.872].
// iv = zv*mag + 127.5 in (8.6,246.4) -> v never clamps, v0+1 in-bounds.
// 24-row v-window coverage proven exhaustively (R5, absmax 0.25; stable R5-R11).
// At s~0 angles 16 x-lanes share u0 while v0 spans ~5 values: pitch 64 put all
// on one bank (5-way serialize, 1.39e8 conflict cyc); pitch 65 spreads them.
// R9's pitch test was confounded by spill (launch_bounds 7); this is the clean
// A/B on the proven R8 base (launch_bounds(256,4), width-4 flat staging).

typedef float v2f __attribute__((ext_vector_type(2)));
typedef __attribute__((address_space(1))) const void gas_t;
typedef __attribute__((address_space(3))) void las_t;

__device__ __forceinline__ int2 bbox_angle(float c, float s,
    float xclo, float xchi, float yclo, float ychi, float zvlo, float zvhi)
{
    const float a0 = xclo*c, a1 = xchi*c, b0 = yclo*s, b1 = ychi*s;
    const float xr0 = a0+b0, xr1 = a0+b1, xr2 = a1+b0, xr3 = a1+b1;
    const float xmn = fminf(fminf(xr0,xr1), fminf(xr2,xr3));
    const float xmx = fmaxf(fmaxf(xr0,xr1), fmaxf(xr2,xr3));
    const float c0 = yclo*c, c1 = ychi*c, d0 = xclo*s, d1 = xchi*s;
    const float yr0 = c0-d0, yr1 = c0-d1, yr2 = c1-d0, yr3 = c1-d1;
    const float ymn = fminf(fminf(yr0,yr1), fminf(yr2,yr3));
    const float ymx = fmaxf(fmaxf(yr0,yr1), fmaxf(yr2,yr3));
    const float mlo = 1536.f * __builtin_amdgcn_rcpf(1000.f - xmn);
    const float mhi = 1536.f * __builtin_amdgcn_rcpf(1000.f - xmx);
    const float umn = fminf(fminf(ymn*mlo, ymn*mhi), fminf(ymx*mlo, ymx*mhi));
    int u_lo = (int)floorf(fmaf(umn, 0.5f, 127.5f)) - 1;
    u_lo = u_lo < 0 ? 0 : (u_lo > ULO_MAX ? ULO_MAX : u_lo);
    const float vmn = fminf(fminf(zvlo*mlo, zvlo*mhi), fminf(zvhi*mlo, zvhi*mhi));
    int v_lo = (int)floorf(vmn + 127.5f) - 1;
    v_lo = v_lo < 0 ? 0 : (v_lo > VLO_MAX ? VLO_MAX : v_lo);
    return make_int2(u_lo, v_lo);
}

// Wave w stages flat floats [w*512 .. w*512+511] of the pitch-65 patch:
// 8 width-4 global_load_lds, LDS dest wave-uniform + lane*4, global source
// per-lane (goffB precomputed once: flat -> detector (row,col) -> bytes).
__device__ __forceinline__ void stage8(const char* gb, float* ldsw,
                                       const int goffB[8]) {
    #pragma unroll
    for (int i = 0; i < 8; ++i) {
        __builtin_amdgcn_global_load_lds(
            (gas_t*)(gb + goffB[i]),
            (las_t*)(ldsw + i * 64), 4, 0, 0);
    }
}

__device__ __forceinline__ void compute_angle(const float* __restrict__ smb,
    float c, float s, float xc, float yc, float zf0, int u_lo, int v_lo,
    v2f acc[ZPT])
{
    const float xr  = xc*c + yc*s;
    const float yr  = yc*c - xc*s;
    const float mag = 1536.f * __builtin_amdgcn_rcpf(1000.f - xr);
    const float iu  = fmaf(yr*mag, 0.5f, 127.5f);
    const bool uval = (iu >= 0.f) && (iu <= 255.f);
    const float iuc = fminf(fmaxf(iu, 0.f), 255.f);
    int u0 = (int)iuc; u0 = u0 > 254 ? 254 : u0;
    const float fu  = iuc - (float)u0;
    const float w   = uval ? 1.f : 0.f;
    const float wu1 = fu*w, wu0 = w - wu1;
    const v2f   wuv = {wu0, wu1};
    const int   ui  = u0 - u_lo;                         // 0..63
    const float ivb = fmaf(zf0, mag, 127.5f) - (float)v_lo;
    #pragma unroll
    for (int k = 0; k < ZPT; ++k) {
        const float ivl = fmaf((float)k, mag, ivb);
        const int   v0  = (int)ivl;                      // >0 -> trunc==floor
        const float fv  = __builtin_amdgcn_fractf(ivl);  // v_fract_f32
        const float* r  = smb + (v0 * PITCH + ui);
        v2f p0 = {r[0],     r[1]};                       // ds_read2_b32
        v2f p1 = {r[PITCH], r[PITCH+1]};                 // offsets 65,66 (imm ok)
        const v2f fvv = {fv, fv};
        const v2f q = __builtin_elementwise_fma(fvv, p1 - p0, p0);
        acc[k] = __builtin_elementwise_fma(wuv, q, acc[k]);
    }
}

__global__ __launch_bounds__(256, 4) void bp_kernel(const float* __restrict__ proj,
                                                    float* __restrict__ out) {
    __shared__ float2 cs_sh[NA];
    __shared__ int2   bb_sh[NA];
    __shared__ float  patch[2][NSTG];

    const int tid = threadIdx.y * 16 + threadIdx.x;

    const int zg = blockIdx.x;            // z-group (16)
    const int t  = blockIdx.y;            // xy tile (64)
    const int b  = blockIdx.z;
    const int x0 = (t & 7) * 16;
    const int y0 = (t >> 3) * 16;
    const int zb = zg * ZPT;

    const float zf0  = (float)zb - 63.5f;
    const float xclo = ((float)x0 - 63.5f) * 2.f, xchi = xclo + 30.f;
    const float yclo = ((float)y0 - 63.5f) * 2.f, ychi = yclo + 30.f;

    for (int i = tid; i < NA; i += 256) {
        float th = (float)i * (float)(2.0 * M_PI / (double)NA);
        float sv, cv; sincosf(th, &sv, &cv);
        cs_sh[i] = make_float2(cv, sv);
        bb_sh[i] = bbox_angle(cv, sv, xclo, xchi, yclo, ychi, zf0, zf0 + 7.f);
    }
    __syncthreads();

    // per-lane staging source offsets (constant across angles)
    const int wv   = tid >> 6;
    const int lane = tid & 63;
    int goffB[8];
    #pragma unroll
    for (int i = 0; i < 8; ++i) {
        const int flat = wv * 512 + i * 64 + lane;
        const int r  = flat / PITCH;          // exact (init-only)
        const int cc = flat - r * PITCH;
        goffB[i] = (r * 256 + cc) * 4;        // detector-row-major, bytes
    }

    const char* projB = (const char*)(proj + (size_t)b * (NA * 65536));
    const float xc = ((float)(x0 + threadIdx.x) - 63.5f) * 2.f;
    const float yc = ((float)(y0 + threadIdx.y) - 63.5f) * 2.f;

    float* l0 = &patch[0][wv * 512];
    float* l1 = &patch[1][wv * 512];

    v2f acc[ZPT];
    #pragma unroll
    for (int k = 0; k < ZPT; ++k) acc[k] = (v2f){0.f, 0.f};

    // prologue: stage angle 0 into patch[0]
    {
        const int2 lo = bb_sh[0];
        const uint32_t aoff = __builtin_amdgcn_readfirstlane(
            ((uint32_t)lo.y << 10) + ((uint32_t)lo.x << 2));
        stage8(projB + aoff, l0, goffB);
    }
    __syncthreads();   // implicit vmcnt(0) drain -> patch[0] ready

    for (int a = 0; a < NA; a += 2) {
        {   // stage a+1 -> patch[1] while computing a from patch[0]
            const int2 lo = bb_sh[a + 1];
            const uint32_t aoff = __builtin_amdgcn_readfirstlane(
                (uint32_t)(a + 1) * 262144u +
                ((uint32_t)lo.y << 10) + ((uint32_t)lo.x << 2));
            stage8(projB + aoff, l1, goffB);
        }
        {
            const float2 cs = cs_sh[a];
            const int2   lo = bb_sh[a];
            compute_angle(patch[0], cs.x, cs.y, xc, yc, zf0, lo.x, lo.y, acc);
        }
        __syncthreads();
        if (a + 2 < NA) {   // stage a+2 -> patch[0] while computing a+1
            const int2 lo = bb_sh[a + 2];
            const uint32_t aoff = __builtin_amdgcn_readfirstlane(
                (uint32_t)(a + 2) * 262144u +
                ((uint32_t)lo.y << 10) + ((uint32_t)lo.x << 2));
            stage8(projB + aoff, l0, goffB);
        }
        {
            const float2 cs = cs_sh[a + 1];
            const int2   lo = bb_sh[a + 1];
            compute_angle(patch[1], cs.x, cs.y, xc, yc, zf0, lo.x, lo.y, acc);
        }
        __syncthreads();
    }

    float* o = out + (((size_t)b * 128 + zb) * 128 + (y0 + threadIdx.y)) * 128
                   + (x0 + threadIdx.x);
    #pragma unroll
    for (int k = 0; k < ZPT; ++k) {
        o[(size_t)k * (128 * 128)] = acc[k].x + acc[k].y;
    }
}

extern "C" void kernel_launch(void* const* d_in, const int* in_sizes, int n_in,
                              void* d_out, int out_size, void* d_ws, size_t ws_size,
                              hipStream_t stream) {
    const float* proj = (const float*)d_in[0];
    float* out = (float*)d_out;
    dim3 grid(128 / ZPT, 64, 2);   // (z-groups, xy-tiles, batch) = 2048 blocks
    dim3 block(16, 16, 1);
    hipLaunchKernelGGL(bp_kernel, grid, block, 0, stream, proj, out);
}